// Round 5
// baseline (325.216 us; speedup 1.0000x reference)
//
#include <hip/hip_runtime.h>
#include <math.h>

#define N_NODES 50000
#define N_EDGES 800000
#define IN_CH   256
#define OUT_CH  64
#define HEADS   4
#define NEG_SLOPE 0.2f
#define NCOLS   320           // W (256) || W_res (64)
#define NTILES  20            // NCOLS / 16
#define NKK     8             // IN_CH / 32
#define PACK_BLOCKS 40        // NKK*NTILES*64 / 256

typedef __attribute__((ext_vector_type(8))) short short8;
typedef __attribute__((ext_vector_type(4))) float f32x4;

__device__ __forceinline__ float lrelu(float v) {
    return v > 0.f ? v : NEG_SLOPE * v;
}
__device__ __forceinline__ unsigned bf16_rne(float f) {
    unsigned u = __float_as_uint(f);
    return (u + 0x7FFFu + ((u >> 16) & 1u)) >> 16;
}
__device__ __forceinline__ unsigned pack2(float lo, float hi) {
    return bf16_rne(lo) | (bf16_rne(hi) << 16);
}
__device__ __forceinline__ float bflo(unsigned u) { return __uint_as_float(u << 16); }
__device__ __forceinline__ float bfhi(unsigned u) { return __uint_as_float(u & 0xFFFF0000u); }
__device__ __forceinline__ short8 as_short8(uint4 u) {
    union { uint4 u4; short8 s8; } cv; cv.u4 = u; return cv.s8;
}

// ---------------------------------------------------------------------------
// prep: fused pack_B (blocks 0..39) + histogram + fill-zero (blocks 40..).
// pack_B: [W | W_res] fp32 -> bf16 MFMA B-fragment order:
//   Bp[(kk*NTILES+t)*64+lane] = 8 bf16: B[kk*32+(lane>>4)*8+j][t*16+(lane&15)]
// ---------------------------------------------------------------------------
__global__ __launch_bounds__(256) void prep(
    const float* __restrict__ W, const float* __restrict__ Wres,
    uint4* __restrict__ Bp, const int* __restrict__ ei,
    int* __restrict__ cnt, int* __restrict__ fill)
{
    if (blockIdx.x < PACK_BLOCKS) {
        const int idx  = blockIdx.x * 256 + threadIdx.x;   // 0..10239
        const int kk   = idx / (NTILES * 64);
        const int rem  = idx - kk * (NTILES * 64);
        const int t    = rem >> 6;
        const int lane = rem & 63;
        const int colL = lane & 15, quad = lane >> 4;
        const int col  = t * 16 + colL;
        const int k0   = kk * 32 + quad * 8;
        float v[8];
        #pragma unroll
        for (int j = 0; j < 8; ++j) {
            const int k = k0 + j;
            v[j] = (col < IN_CH) ? W[(size_t)k * IN_CH + col]
                                 : Wres[(size_t)k * OUT_CH + (col - IN_CH)];
        }
        uint4 u;
        u.x = pack2(v[0], v[1]); u.y = pack2(v[2], v[3]);
        u.z = pack2(v[4], v[5]); u.w = pack2(v[6], v[7]);
        Bp[(kk * NTILES + t) * 64 + lane] = u;
    } else {
        const int e = (blockIdx.x - PACK_BLOCKS) * 256 + threadIdx.x;
        if (e < N_NODES) fill[e] = 0;       // consumed only by scatter (later)
        if (e < N_EDGES) atomicAdd(&cnt[ei[N_EDGES + e]], 1);
    }
}

// ---------------------------------------------------------------------------
// scan: single block, 1024 threads; exclusive scan of cnt -> rowstart[0..N-1],
// total -> rowstart[N] (sentinel, so consumers get deg = diff).
// ---------------------------------------------------------------------------
__global__ __launch_bounds__(1024) void scan_kernel(
    const int* __restrict__ cnt, int* __restrict__ rowstart)
{
    __shared__ int wsums[16];
    __shared__ int carry_s;
    const int t = threadIdx.x;
    const int lane = t & 63, w = t >> 6;
    if (t == 0) carry_s = 0;
    __syncthreads();
    for (int base = 0; base < N_NODES; base += 1024) {
        const int i = base + t;
        const int v = (i < N_NODES) ? cnt[i] : 0;
        int sc = v;
        #pragma unroll
        for (int off = 1; off < 64; off <<= 1) {
            const int n = __shfl_up(sc, off);
            if (lane >= off) sc += n;
        }
        if (lane == 63) wsums[w] = sc;
        __syncthreads();
        if (t < 16) {
            int s = wsums[t];
            #pragma unroll
            for (int off = 1; off < 16; off <<= 1) {
                const int n = __shfl_up(s, off);
                if (t >= off) s += n;
            }
            wsums[t] = s;
        }
        __syncthreads();
        const int wofs = (w == 0) ? 0 : wsums[w - 1];
        if (i < N_NODES) rowstart[i] = carry_s + wofs + sc - v;
        __syncthreads();
        if (t == 0) carry_s += wsums[15];
        __syncthreads();
    }
    if (t == 0) rowstart[N_NODES] = carry_s;
}

__global__ __launch_bounds__(256) void scatter(
    const int* __restrict__ ei, const int* __restrict__ rowstart,
    int* __restrict__ fill, int* __restrict__ esrc)
{
    const int e = blockIdx.x * 256 + threadIdx.x;
    if (e >= N_EDGES) return;
    const int d = ei[N_EDGES + e];
    const int pos = atomicAdd(&fill[d], 1);
    esrc[rowstart[d] + pos] = ei[e];
}

// ---------------------------------------------------------------------------
// MFMA node transform (unchanged from R4 — working). Block = 4 waves,
// 64 nodes; wave wv owns col-tiles {wv,4+wv,8+wv,12+wv,16+wv} over all 4
// row-groups (each B tile read once per block). Cross-wave logit reduction
// via LDS keeps fp32 accuracy. C/D: col=lane&15, row=(lane>>4)*4+reg.
// ---------------------------------------------------------------------------
__global__ __launch_bounds__(256) void gemm_node(
    const float* __restrict__ x, const uint4* __restrict__ Bp,
    const float* __restrict__ attS, const float* __restrict__ attD,
    unsigned* __restrict__ xwp, float* __restrict__ xres,
    float* __restrict__ asrc, float* __restrict__ adst)
{
    __shared__ uint4 Alds[4 * NKK * 64];   // 32 KB
    __shared__ float partS[4][4][64];
    __shared__ float partD[4][4][64];
    const int tid = threadIdx.x;
    const int n0  = blockIdx.x * 64;

    #pragma unroll
    for (int i = 0; i < 8; ++i) {
        const int e    = i * 256 + tid;
        const int g    = e >> 9;
        const int kk   = (e >> 6) & 7;
        const int lane = e & 63;
        const int cL   = lane & 15, qd = lane >> 4;
        const int row  = n0 + g * 16 + cL;
        const int k0   = kk * 32 + qd * 8;
        uint4 u = make_uint4(0u, 0u, 0u, 0u);
        if (row < N_NODES) {
            const float4 a = *reinterpret_cast<const float4*>(x + (size_t)row * IN_CH + k0);
            const float4 b = *reinterpret_cast<const float4*>(x + (size_t)row * IN_CH + k0 + 4);
            u.x = pack2(a.x, a.y); u.y = pack2(a.z, a.w);
            u.z = pack2(b.x, b.y); u.w = pack2(b.z, b.w);
        }
        Alds[(g * NKK + kk) * 64 + lane] = u;
    }
    __syncthreads();

    const int lane = tid & 63;
    const int wv   = tid >> 6;
    const int colL = lane & 15, quad = lane >> 4;

    f32x4 acc[4][5];
    #pragma unroll
    for (int rg = 0; rg < 4; ++rg)
        #pragma unroll
        for (int j = 0; j < 5; ++j) acc[rg][j] = (f32x4){0.f, 0.f, 0.f, 0.f};

    for (int kk = 0; kk < NKK; ++kk) {
        uint4 bu[5];
        #pragma unroll
        for (int j = 0; j < 5; ++j)
            bu[j] = Bp[(kk * NTILES + j * 4 + wv) * 64 + lane];
        #pragma unroll
        for (int rg = 0; rg < 4; ++rg) {
            const short8 a = as_short8(Alds[(rg * NKK + kk) * 64 + lane]);
            #pragma unroll
            for (int j = 0; j < 5; ++j)
                acc[rg][j] = __builtin_amdgcn_mfma_f32_16x16x32_bf16(
                    a, as_short8(bu[j]), acc[rg][j], 0, 0, 0);
        }
    }

    #pragma unroll
    for (int h = 0; h < HEADS; ++h) {
        const float aSv = attS[h * 64 + wv * 16 + colL];
        const float aDv = attD[h * 64 + wv * 16 + colL];
        #pragma unroll
        for (int rg = 0; rg < 4; ++rg) {
            #pragma unroll
            for (int r = 0; r < 4; ++r) {
                float vs = acc[rg][h][r] * aSv;
                float vd = acc[rg][h][r] * aDv;
                #pragma unroll
                for (int off = 8; off >= 1; off >>= 1) {
                    vs += __shfl_xor(vs, off);
                    vd += __shfl_xor(vd, off);
                }
                if (colL == 0) {
                    partS[wv][h][rg * 16 + quad * 4 + r] = vs;
                    partD[wv][h][rg * 16 + quad * 4 + r] = vd;
                }
            }
        }
    }
    __syncthreads();
    {
        const int rowIB = tid & 63, h = tid >> 6;
        const int row = n0 + rowIB;
        if (row < N_NODES) {
            const float vs = partS[0][h][rowIB] + partS[1][h][rowIB]
                           + partS[2][h][rowIB] + partS[3][h][rowIB];
            const float vd = partD[0][h][rowIB] + partD[1][h][rowIB]
                           + partD[2][h][rowIB] + partD[3][h][rowIB];
            asrc[row * HEADS + h] = vs;
            adst[row * HEADS + h] = vd;
        }
    }

    #pragma unroll
    for (int hp = 0; hp < 2; ++hp) {
        #pragma unroll
        for (int rg = 0; rg < 4; ++rg) {
            #pragma unroll
            for (int r = 0; r < 4; ++r) {
                const int row = n0 + rg * 16 + quad * 4 + r;
                if (row < N_NODES)
                    xwp[(size_t)row * 128 + hp * 64 + wv * 16 + colL] =
                        pack2(acc[rg][hp * 2][r], acc[rg][hp * 2 + 1][r]);
            }
        }
    }
    #pragma unroll
    for (int rg = 0; rg < 4; ++rg) {
        #pragma unroll
        for (int r = 0; r < 4; ++r) {
            const int row = n0 + rg * 16 + quad * 4 + r;
            if (row < N_NODES)
                xres[(size_t)row * OUT_CH + wv * 16 + colL] = acc[rg][4][r];
        }
    }
}

// ---------------------------------------------------------------------------
// aggregate, single-pass: 4 UNNORMALIZED head accumulators; normalization is
// a per-head scalar applied once at the end, so no denominator pre-pass and
// no ew round-trip. Per 64-edge chunk: lane-parallel gather asrc + exp ->
// stash (w0..w3, src*512) in per-wave LDS; per edge: uniform-addr LDS
// broadcast + 2 xwp gathers + 4 fma. One wave per dst node, lane = channel.
// ---------------------------------------------------------------------------
__global__ __launch_bounds__(256) void aggregate(
    const int* __restrict__ esrc, const int* __restrict__ rowstart,
    const float* __restrict__ asrc, const float* __restrict__ adst,
    const unsigned* __restrict__ xwp, const float* __restrict__ xres,
    const float* __restrict__ bias, float* __restrict__ out)
{
    __shared__ float4 wbuf[4][64];   // [wave][edge-in-chunk] exp quadruple
    __shared__ int    sbuf[4][64];   // [wave][edge-in-chunk] src byte offset
    const int lane = threadIdx.x & 63;
    const int wv   = threadIdx.x >> 6;
    const int d = blockIdx.x * 4 + wv;
    if (d >= N_NODES) return;
    const int row = rowstart[d];
    const int deg = rowstart[d + 1] - row;
    const float4 ad = *reinterpret_cast<const float4*>(adst + (size_t)d * 4);
    const char* xwpB = (const char*)xwp;

    float dn0 = 0.f, dn1 = 0.f, dn2 = 0.f, dn3 = 0.f;
    float ac0 = 0.f, ac1 = 0.f, ac2 = 0.f, ac3 = 0.f;

    for (int base = 0; base < deg; base += 64) {
        const int m = min(64, deg - base);
        // lane-parallel: edge base+lane
        if (lane < m) {
            const int s = esrc[row + base + lane];
            const float4 as = *reinterpret_cast<const float4*>(asrc + (size_t)s * 4);
            const float e0 = __expf(lrelu(as.x + ad.x));
            const float e1 = __expf(lrelu(as.y + ad.y));
            const float e2 = __expf(lrelu(as.z + ad.z));
            const float e3 = __expf(lrelu(as.w + ad.w));
            dn0 += e0; dn1 += e1; dn2 += e2; dn3 += e3;
            wbuf[wv][lane] = make_float4(e0, e1, e2, e3);
            sbuf[wv][lane] = s << 9;   // *512 bytes
        }
        int j = 0;
        for (; j + 4 <= m; j += 4) {
            const float4 wA = wbuf[wv][j];
            const float4 wB = wbuf[wv][j + 1];
            const float4 wC = wbuf[wv][j + 2];
            const float4 wD = wbuf[wv][j + 3];
            const int sA = sbuf[wv][j];
            const int sB = sbuf[wv][j + 1];
            const int sC = sbuf[wv][j + 2];
            const int sD = sbuf[wv][j + 3];
            const unsigned a0 = *(const unsigned*)(xwpB + sA + (lane << 2));
            const unsigned a1 = *(const unsigned*)(xwpB + sA + 256 + (lane << 2));
            const unsigned b0 = *(const unsigned*)(xwpB + sB + (lane << 2));
            const unsigned b1 = *(const unsigned*)(xwpB + sB + 256 + (lane << 2));
            const unsigned c0 = *(const unsigned*)(xwpB + sC + (lane << 2));
            const unsigned c1 = *(const unsigned*)(xwpB + sC + 256 + (lane << 2));
            const unsigned d0 = *(const unsigned*)(xwpB + sD + (lane << 2));
            const unsigned d1 = *(const unsigned*)(xwpB + sD + 256 + (lane << 2));
            ac0 = fmaf(wA.x, bflo(a0), ac0); ac1 = fmaf(wA.y, bfhi(a0), ac1);
            ac2 = fmaf(wA.z, bflo(a1), ac2); ac3 = fmaf(wA.w, bfhi(a1), ac3);
            ac0 = fmaf(wB.x, bflo(b0), ac0); ac1 = fmaf(wB.y, bfhi(b0), ac1);
            ac2 = fmaf(wB.z, bflo(b1), ac2); ac3 = fmaf(wB.w, bfhi(b1), ac3);
            ac0 = fmaf(wC.x, bflo(c0), ac0); ac1 = fmaf(wC.y, bfhi(c0), ac1);
            ac2 = fmaf(wC.z, bflo(c1), ac2); ac3 = fmaf(wC.w, bfhi(c1), ac3);
            ac0 = fmaf(wD.x, bflo(d0), ac0); ac1 = fmaf(wD.y, bfhi(d0), ac1);
            ac2 = fmaf(wD.z, bflo(d1), ac2); ac3 = fmaf(wD.w, bfhi(d1), ac3);
        }
        for (; j < m; ++j) {
            const float4 w = wbuf[wv][j];
            const int sj = sbuf[wv][j];
            const unsigned v0 = *(const unsigned*)(xwpB + sj + (lane << 2));
            const unsigned v1 = *(const unsigned*)(xwpB + sj + 256 + (lane << 2));
            ac0 = fmaf(w.x, bflo(v0), ac0); ac1 = fmaf(w.y, bfhi(v0), ac1);
            ac2 = fmaf(w.z, bflo(v1), ac2); ac3 = fmaf(w.w, bfhi(v1), ac3);
        }
    }

    // reduce denominators across lanes
    #pragma unroll
    for (int off = 32; off >= 1; off >>= 1) {
        dn0 += __shfl_xor(dn0, off);
        dn1 += __shfl_xor(dn1, off);
        dn2 += __shfl_xor(dn2, off);
        dn3 += __shfl_xor(dn3, off);
    }
    // self-loop
    const float4 asd = *reinterpret_cast<const float4*>(asrc + (size_t)d * 4);
    const float s0 = __expf(lrelu(asd.x + ad.x));
    const float s1 = __expf(lrelu(asd.y + ad.y));
    const float s2 = __expf(lrelu(asd.z + ad.z));
    const float s3 = __expf(lrelu(asd.w + ad.w));
    const unsigned u0 = xwp[(size_t)d * 128 + lane];
    const unsigned u1 = xwp[(size_t)d * 128 + 64 + lane];
    ac0 = fmaf(s0, bflo(u0), ac0); ac1 = fmaf(s1, bfhi(u0), ac1);
    ac2 = fmaf(s2, bflo(u1), ac2); ac3 = fmaf(s3, bfhi(u1), ac3);
    const float i0 = 0.25f / (dn0 + s0);
    const float i1 = 0.25f / (dn1 + s1);
    const float i2 = 0.25f / (dn2 + s2);
    const float i3 = 0.25f / (dn3 + s3);
    const float v = ac0 * i0 + ac1 * i1 + ac2 * i2 + ac3 * i3
                  + bias[lane] + xres[(size_t)d * OUT_CH + lane];
    out[(size_t)d * OUT_CH + lane] = fmaxf(v, 0.f);
}

extern "C" void kernel_launch(void* const* d_in, const int* in_sizes, int n_in,
                              void* d_out, int out_size, void* d_ws, size_t ws_size,
                              hipStream_t stream) {
    const float* x    = (const float*)d_in[0];
    const int*   ei   = (const int*)d_in[1];
    const float* W    = (const float*)d_in[2];
    const float* attS = (const float*)d_in[3];
    const float* attD = (const float*)d_in[4];
    const float* bias = (const float*)d_in[5];
    const float* Wres = (const float*)d_in[6];
    float* out = (float*)d_out;

    char* p = (char*)d_ws;
    uint4*    Bp       = (uint4*)p;    p += (size_t)NKK * NTILES * 64 * 16;  // 160 KB
    unsigned* xwp      = (unsigned*)p; p += (size_t)N_NODES * 128 * 4;       // 25.6 MB
    float*    xres     = (float*)p;    p += (size_t)N_NODES * OUT_CH * 4;    // 12.8 MB
    float*    asrc     = (float*)p;    p += (size_t)N_NODES * HEADS * 4;
    float*    adst     = (float*)p;    p += (size_t)N_NODES * HEADS * 4;
    int*      cnt      = (int*)p;      p += (size_t)N_NODES * 4;
    int*      fill     = (int*)p;      p += (size_t)N_NODES * 4;
    int*      rowstart = (int*)p;      p += (size_t)(N_NODES + 1) * 4;
    int*      esrc     = (int*)p;      p += (size_t)N_EDGES * 4;

    hipMemsetAsync(cnt, 0, (size_t)N_NODES * sizeof(int), stream);

    prep<<<PACK_BLOCKS + (N_EDGES + 255) / 256, 256, 0, stream>>>(
        W, Wres, Bp, ei, cnt, fill);
    scan_kernel<<<1, 1024, 0, stream>>>(cnt, rowstart);
    scatter<<<(N_EDGES + 255) / 256, 256, 0, stream>>>(ei, rowstart, fill, esrc);
    gemm_node<<<(N_NODES + 63) / 64, 256, 0, stream>>>(
        x, Bp, attS, attD, xwp, xres, asrc, adst);
    aggregate<<<(N_NODES + 3) / 4, 256, 0, stream>>>(
        esrc, rowstart, asrc, adst, xwp, xres, bias, out);
}

// Round 6
// 296.720 us; speedup vs baseline: 1.0960x; 1.0960x over previous
//
#include <hip/hip_runtime.h>
#include <math.h>

#define N_NODES 50000
#define N_EDGES 800000
#define IN_CH   256
#define OUT_CH  64
#define HEADS   4
#define NEG_SLOPE 0.2f
#define NCOLS   320           // W (256) || W_res (64)
#define NTILES  20            // NCOLS / 16
#define NKK     8             // IN_CH / 32
#define PACK_BLOCKS 40        // NKK*NTILES*64 / 256

typedef __attribute__((ext_vector_type(8))) short short8;
typedef __attribute__((ext_vector_type(4))) float f32x4;

__device__ __forceinline__ float lrelu(float v) {
    return v > 0.f ? v : NEG_SLOPE * v;
}
__device__ __forceinline__ unsigned bf16_rne(float f) {
    unsigned u = __float_as_uint(f);
    return (u + 0x7FFFu + ((u >> 16) & 1u)) >> 16;
}
__device__ __forceinline__ unsigned pack2(float lo, float hi) {
    return bf16_rne(lo) | (bf16_rne(hi) << 16);
}
__device__ __forceinline__ float bflo(unsigned u) { return __uint_as_float(u << 16); }
__device__ __forceinline__ float bfhi(unsigned u) { return __uint_as_float(u & 0xFFFF0000u); }
__device__ __forceinline__ short8 as_short8(uint4 u) {
    union { uint4 u4; short8 s8; } cv; cv.u4 = u; return cv.s8;
}

// ---------------------------------------------------------------------------
// prep: fused pack_B (blocks 0..39) + histogram + fill-zero (blocks 40..).
// pack_B: [W | W_res] fp32 -> bf16 MFMA B-fragment order:
//   Bp[(kk*NTILES+t)*64+lane] = 8 bf16: B[kk*32+(lane>>4)*8+j][t*16+(lane&15)]
// ---------------------------------------------------------------------------
__global__ __launch_bounds__(256) void prep(
    const float* __restrict__ W, const float* __restrict__ Wres,
    uint4* __restrict__ Bp, const int* __restrict__ ei,
    int* __restrict__ cnt, int* __restrict__ fill)
{
    if (blockIdx.x < PACK_BLOCKS) {
        const int idx  = blockIdx.x * 256 + threadIdx.x;   // 0..10239
        const int kk   = idx / (NTILES * 64);
        const int rem  = idx - kk * (NTILES * 64);
        const int t    = rem >> 6;
        const int lane = rem & 63;
        const int colL = lane & 15, quad = lane >> 4;
        const int col  = t * 16 + colL;
        const int k0   = kk * 32 + quad * 8;
        float v[8];
        #pragma unroll
        for (int j = 0; j < 8; ++j) {
            const int k = k0 + j;
            v[j] = (col < IN_CH) ? W[(size_t)k * IN_CH + col]
                                 : Wres[(size_t)k * OUT_CH + (col - IN_CH)];
        }
        uint4 u;
        u.x = pack2(v[0], v[1]); u.y = pack2(v[2], v[3]);
        u.z = pack2(v[4], v[5]); u.w = pack2(v[6], v[7]);
        Bp[(kk * NTILES + t) * 64 + lane] = u;
    } else {
        const int e = (blockIdx.x - PACK_BLOCKS) * 256 + threadIdx.x;
        if (e < N_NODES) fill[e] = 0;       // consumed only by scatter (later)
        if (e < N_EDGES) atomicAdd(&cnt[ei[N_EDGES + e]], 1);
    }
}

// ---------------------------------------------------------------------------
// 2-level exclusive scan (parallel): scan_local over 256-chunks + scan_bsum
// over the 196 block sums. Consumers add bsumx[i>>8].
// ---------------------------------------------------------------------------
__global__ __launch_bounds__(256) void scan_local(
    const int* __restrict__ cnt, int* __restrict__ lscan, int* __restrict__ bsum)
{
    __shared__ int ws[4];
    const int t = threadIdx.x, lane = t & 63, w = t >> 6;
    const int i = blockIdx.x * 256 + t;
    const int v = (i < N_NODES) ? cnt[i] : 0;
    int sc = v;
    #pragma unroll
    for (int off = 1; off < 64; off <<= 1) {
        const int n = __shfl_up(sc, off);
        if (lane >= off) sc += n;
    }
    if (lane == 63) ws[w] = sc;
    __syncthreads();
    int prefix = 0;
    for (int j = 0; j < w; ++j) prefix += ws[j];
    if (i < N_NODES) lscan[i] = prefix + sc - v;
    if (t == 255) bsum[blockIdx.x] = prefix + sc;
}

__global__ __launch_bounds__(256) void scan_bsum(
    const int* __restrict__ bsum, int* __restrict__ bsumx, int nblk)
{
    __shared__ int ws[4];
    const int t = threadIdx.x, lane = t & 63, w = t >> 6;
    const int v = (t < nblk) ? bsum[t] : 0;
    int sc = v;
    #pragma unroll
    for (int off = 1; off < 64; off <<= 1) {
        const int n = __shfl_up(sc, off);
        if (lane >= off) sc += n;
    }
    if (lane == 63) ws[w] = sc;
    __syncthreads();
    int prefix = 0;
    for (int j = 0; j < w; ++j) prefix += ws[j];
    if (t < nblk) bsumx[t] = prefix + sc - v;
}

__global__ __launch_bounds__(256) void scatter(
    const int* __restrict__ ei, const int* __restrict__ lscan,
    const int* __restrict__ bsumx, int* __restrict__ fill, int* __restrict__ esrc)
{
    const int e = blockIdx.x * 256 + threadIdx.x;
    if (e >= N_EDGES) return;
    const int d = ei[N_EDGES + e];
    const int pos = atomicAdd(&fill[d], 1);
    esrc[lscan[d] + bsumx[d >> 8] + pos] = ei[e];
}

// ---------------------------------------------------------------------------
// MFMA node transform. Block = 4 waves, 64 nodes; wave wv owns col-tiles
// {wv,4+wv,8+wv,12+wv,16+wv} over all 4 row-groups (each B tile read once per
// block). Cross-wave logit reduction via LDS keeps fp32 accuracy.
// C/D: col=lane&15, row=(lane>>4)*4+reg.
// xw stored as uint2 per (node,lane): .x=(h0,h1) .y=(h2,h3) packed bf16 --
// single dwordx2 gather per edge in aggregate.
// ---------------------------------------------------------------------------
__global__ __launch_bounds__(256) void gemm_node(
    const float* __restrict__ x, const uint4* __restrict__ Bp,
    const float* __restrict__ attS, const float* __restrict__ attD,
    uint2* __restrict__ xw2, float* __restrict__ xres,
    float* __restrict__ asrc, float* __restrict__ adst)
{
    __shared__ uint4 Alds[4 * NKK * 64];   // 32 KB
    __shared__ float partS[4][4][64];
    __shared__ float partD[4][4][64];
    const int tid = threadIdx.x;
    const int n0  = blockIdx.x * 64;

    #pragma unroll
    for (int i = 0; i < 8; ++i) {
        const int e    = i * 256 + tid;
        const int g    = e >> 9;
        const int kk   = (e >> 6) & 7;
        const int lane = e & 63;
        const int cL   = lane & 15, qd = lane >> 4;
        const int row  = n0 + g * 16 + cL;
        const int k0   = kk * 32 + qd * 8;
        uint4 u = make_uint4(0u, 0u, 0u, 0u);
        if (row < N_NODES) {
            const float4 a = *reinterpret_cast<const float4*>(x + (size_t)row * IN_CH + k0);
            const float4 b = *reinterpret_cast<const float4*>(x + (size_t)row * IN_CH + k0 + 4);
            u.x = pack2(a.x, a.y); u.y = pack2(a.z, a.w);
            u.z = pack2(b.x, b.y); u.w = pack2(b.z, b.w);
        }
        Alds[(g * NKK + kk) * 64 + lane] = u;
    }
    __syncthreads();

    const int lane = tid & 63;
    const int wv   = tid >> 6;
    const int colL = lane & 15, quad = lane >> 4;

    f32x4 acc[4][5];
    #pragma unroll
    for (int rg = 0; rg < 4; ++rg)
        #pragma unroll
        for (int j = 0; j < 5; ++j) acc[rg][j] = (f32x4){0.f, 0.f, 0.f, 0.f};

    for (int kk = 0; kk < NKK; ++kk) {
        uint4 bu[5];
        #pragma unroll
        for (int j = 0; j < 5; ++j)
            bu[j] = Bp[(kk * NTILES + j * 4 + wv) * 64 + lane];
        #pragma unroll
        for (int rg = 0; rg < 4; ++rg) {
            const short8 a = as_short8(Alds[(rg * NKK + kk) * 64 + lane]);
            #pragma unroll
            for (int j = 0; j < 5; ++j)
                acc[rg][j] = __builtin_amdgcn_mfma_f32_16x16x32_bf16(
                    a, as_short8(bu[j]), acc[rg][j], 0, 0, 0);
        }
    }

    #pragma unroll
    for (int h = 0; h < HEADS; ++h) {
        const float aSv = attS[h * 64 + wv * 16 + colL];
        const float aDv = attD[h * 64 + wv * 16 + colL];
        #pragma unroll
        for (int rg = 0; rg < 4; ++rg) {
            #pragma unroll
            for (int r = 0; r < 4; ++r) {
                float vs = acc[rg][h][r] * aSv;
                float vd = acc[rg][h][r] * aDv;
                #pragma unroll
                for (int off = 8; off >= 1; off >>= 1) {
                    vs += __shfl_xor(vs, off);
                    vd += __shfl_xor(vd, off);
                }
                if (colL == 0) {
                    partS[wv][h][rg * 16 + quad * 4 + r] = vs;
                    partD[wv][h][rg * 16 + quad * 4 + r] = vd;
                }
            }
        }
    }
    __syncthreads();
    {
        const int rowIB = tid & 63, h = tid >> 6;
        const int row = n0 + rowIB;
        if (row < N_NODES) {
            const float vs = partS[0][h][rowIB] + partS[1][h][rowIB]
                           + partS[2][h][rowIB] + partS[3][h][rowIB];
            const float vd = partD[0][h][rowIB] + partD[1][h][rowIB]
                           + partD[2][h][rowIB] + partD[3][h][rowIB];
            asrc[row * HEADS + h] = vs;
            adst[row * HEADS + h] = vd;
        }
    }

    // xw2: one uint2 per (row, col) — (h0,h1) in .x, (h2,h3) in .y
    #pragma unroll
    for (int rg = 0; rg < 4; ++rg) {
        #pragma unroll
        for (int r = 0; r < 4; ++r) {
            const int row = n0 + rg * 16 + quad * 4 + r;
            if (row < N_NODES) {
                xw2[(size_t)row * 64 + wv * 16 + colL] = make_uint2(
                    pack2(acc[rg][0][r], acc[rg][1][r]),
                    pack2(acc[rg][2][r], acc[rg][3][r]));
                xres[(size_t)row * OUT_CH + wv * 16 + colL] = acc[rg][4][r];
            }
        }
    }
}

// ---------------------------------------------------------------------------
// aggregate, single-pass, unnormalized head accumulators (normalize once at
// the end). Per 64-edge chunk: lane-parallel gather asrc + exp -> LDS stash;
// per edge: uniform-addr LDS broadcast + ONE dwordx2 gather + 4 fma.
// 8x unrolled -> 8 outstanding gathers. One wave per dst node, lane=channel.
// ---------------------------------------------------------------------------
__global__ __launch_bounds__(256) void aggregate(
    const int* __restrict__ esrc, const int* __restrict__ lscan,
    const int* __restrict__ bsumx, const int* __restrict__ cnt,
    const float* __restrict__ asrc, const float* __restrict__ adst,
    const uint2* __restrict__ xw2, const float* __restrict__ xres,
    const float* __restrict__ bias, float* __restrict__ out)
{
    __shared__ float4 wbuf[4][64];
    __shared__ int    sbuf[4][64];
    const int lane = threadIdx.x & 63;
    const int wv   = threadIdx.x >> 6;
    const int d = blockIdx.x * 4 + wv;
    if (d >= N_NODES) return;
    const int row = lscan[d] + bsumx[d >> 8];
    const int deg = cnt[d];
    const float4 ad = *reinterpret_cast<const float4*>(adst + (size_t)d * 4);
    const char* xwB = (const char*)xw2;
    const int laneB = lane << 3;

    float dn0 = 0.f, dn1 = 0.f, dn2 = 0.f, dn3 = 0.f;
    float ac0 = 0.f, ac1 = 0.f, ac2 = 0.f, ac3 = 0.f;

    for (int base = 0; base < deg; base += 64) {
        const int m = min(64, deg - base);
        if (lane < m) {
            const int s = esrc[row + base + lane];
            const float4 as = *reinterpret_cast<const float4*>(asrc + (size_t)s * 4);
            const float e0 = __expf(lrelu(as.x + ad.x));
            const float e1 = __expf(lrelu(as.y + ad.y));
            const float e2 = __expf(lrelu(as.z + ad.z));
            const float e3 = __expf(lrelu(as.w + ad.w));
            dn0 += e0; dn1 += e1; dn2 += e2; dn3 += e3;
            wbuf[wv][lane] = make_float4(e0, e1, e2, e3);
            sbuf[wv][lane] = s << 9;   // *512 bytes per node row
        }
        int j = 0;
        for (; j + 8 <= m; j += 8) {
            uint2 v[8]; float4 w[8];
            #pragma unroll
            for (int q = 0; q < 8; ++q) {
                w[q] = wbuf[wv][j + q];
                v[q] = *(const uint2*)(xwB + sbuf[wv][j + q] + laneB);
            }
            #pragma unroll
            for (int q = 0; q < 8; ++q) {
                ac0 = fmaf(w[q].x, bflo(v[q].x), ac0);
                ac1 = fmaf(w[q].y, bfhi(v[q].x), ac1);
                ac2 = fmaf(w[q].z, bflo(v[q].y), ac2);
                ac3 = fmaf(w[q].w, bfhi(v[q].y), ac3);
            }
        }
        for (; j < m; ++j) {
            const float4 w = wbuf[wv][j];
            const uint2 v = *(const uint2*)(xwB + sbuf[wv][j] + laneB);
            ac0 = fmaf(w.x, bflo(v.x), ac0);
            ac1 = fmaf(w.y, bfhi(v.x), ac1);
            ac2 = fmaf(w.z, bflo(v.y), ac2);
            ac3 = fmaf(w.w, bfhi(v.y), ac3);
        }
    }

    #pragma unroll
    for (int off = 32; off >= 1; off >>= 1) {
        dn0 += __shfl_xor(dn0, off);
        dn1 += __shfl_xor(dn1, off);
        dn2 += __shfl_xor(dn2, off);
        dn3 += __shfl_xor(dn3, off);
    }
    // self-loop
    const float4 asd = *reinterpret_cast<const float4*>(asrc + (size_t)d * 4);
    const float s0 = __expf(lrelu(asd.x + ad.x));
    const float s1 = __expf(lrelu(asd.y + ad.y));
    const float s2 = __expf(lrelu(asd.z + ad.z));
    const float s3 = __expf(lrelu(asd.w + ad.w));
    const uint2 u = xw2[(size_t)d * 64 + lane];
    ac0 = fmaf(s0, bflo(u.x), ac0); ac1 = fmaf(s1, bfhi(u.x), ac1);
    ac2 = fmaf(s2, bflo(u.y), ac2); ac3 = fmaf(s3, bfhi(u.y), ac3);
    const float i0 = 0.25f / (dn0 + s0);
    const float i1 = 0.25f / (dn1 + s1);
    const float i2 = 0.25f / (dn2 + s2);
    const float i3 = 0.25f / (dn3 + s3);
    const float v = ac0 * i0 + ac1 * i1 + ac2 * i2 + ac3 * i3
                  + bias[lane] + xres[(size_t)d * OUT_CH + lane];
    out[(size_t)d * OUT_CH + lane] = fmaxf(v, 0.f);
}

extern "C" void kernel_launch(void* const* d_in, const int* in_sizes, int n_in,
                              void* d_out, int out_size, void* d_ws, size_t ws_size,
                              hipStream_t stream) {
    const float* x    = (const float*)d_in[0];
    const int*   ei   = (const int*)d_in[1];
    const float* W    = (const float*)d_in[2];
    const float* attS = (const float*)d_in[3];
    const float* attD = (const float*)d_in[4];
    const float* bias = (const float*)d_in[5];
    const float* Wres = (const float*)d_in[6];
    float* out = (float*)d_out;

    char* p = (char*)d_ws;
    uint4*    Bp    = (uint4*)p;    p += (size_t)NKK * NTILES * 64 * 16;  // 160 KB
    uint2*    xw2   = (uint2*)p;    p += (size_t)N_NODES * 64 * 8;        // 25.6 MB
    float*    xres  = (float*)p;    p += (size_t)N_NODES * OUT_CH * 4;    // 12.8 MB
    float*    asrc  = (float*)p;    p += (size_t)N_NODES * HEADS * 4;
    float*    adst  = (float*)p;    p += (size_t)N_NODES * HEADS * 4;
    int*      cnt   = (int*)p;      p += (size_t)N_NODES * 4;
    int*      fill  = (int*)p;      p += (size_t)N_NODES * 4;
    int*      lscan = (int*)p;      p += (size_t)N_NODES * 4;
    int*      bsum  = (int*)p;      p += 256 * 4;
    int*      bsumx = (int*)p;      p += 256 * 4;
    int*      esrc  = (int*)p;      p += (size_t)N_EDGES * 4;

    const int nblk_scan = (N_NODES + 255) / 256;   // 196

    hipMemsetAsync(cnt, 0, (size_t)N_NODES * sizeof(int), stream);

    prep<<<PACK_BLOCKS + (N_EDGES + 255) / 256, 256, 0, stream>>>(
        W, Wres, Bp, ei, cnt, fill);
    scan_local<<<nblk_scan, 256, 0, stream>>>(cnt, lscan, bsum);
    scan_bsum<<<1, 256, 0, stream>>>(bsum, bsumx, nblk_scan);
    scatter<<<(N_EDGES + 255) / 256, 256, 0, stream>>>(ei, lscan, bsumx, fill, esrc);
    gemm_node<<<(N_NODES + 63) / 64, 256, 0, stream>>>(
        x, Bp, attS, attD, xw2, xres, asrc, adst);
    aggregate<<<(N_NODES + 3) / 4, 256, 0, stream>>>(
        esrc, lscan, bsumx, cnt, asrc, adst, xw2, xres, bias, out);
}

// Round 7
// 263.729 us; speedup vs baseline: 1.2331x; 1.1251x over previous
//
#include <hip/hip_runtime.h>
#include <math.h>

#define N_NODES 50000
#define N_EDGES 800000
#define IN_CH   256
#define OUT_CH  64
#define HEADS   4
#define NEG_SLOPE 0.2f
#define NCOLS   320           // W (256) || W_res (64)
#define NTILES  20            // NCOLS / 16
#define NKK     8             // IN_CH / 32
#define PACK_BLOCKS 40        // NKK*NTILES*64 / 256
#define GEMM_BLOCKS 782       // (N_NODES+63)/64
#define SCAT_BLOCKS 3125      // N_EDGES/256

typedef __attribute__((ext_vector_type(8))) short short8;
typedef __attribute__((ext_vector_type(4))) float f32x4;

__device__ __forceinline__ float lrelu(float v) {
    return v > 0.f ? v : NEG_SLOPE * v;
}
__device__ __forceinline__ unsigned bf16_rne(float f) {
    unsigned u = __float_as_uint(f);
    return (u + 0x7FFFu + ((u >> 16) & 1u)) >> 16;
}
__device__ __forceinline__ unsigned pack2(float lo, float hi) {
    return bf16_rne(lo) | (bf16_rne(hi) << 16);
}
__device__ __forceinline__ float bflo(unsigned u) { return __uint_as_float(u << 16); }
__device__ __forceinline__ float bfhi(unsigned u) { return __uint_as_float(u & 0xFFFF0000u); }
__device__ __forceinline__ short8 as_short8(uint4 u) {
    union { uint4 u4; short8 s8; } cv; cv.u4 = u; return cv.s8;
}

// ---------------------------------------------------------------------------
// prep: fused pack_B (blocks 0..39) + histogram + fill-zero (blocks 40..).
// ---------------------------------------------------------------------------
__global__ __launch_bounds__(256) void prep(
    const float* __restrict__ W, const float* __restrict__ Wres,
    uint4* __restrict__ Bp, const int* __restrict__ ei,
    int* __restrict__ cnt, int* __restrict__ fill)
{
    if (blockIdx.x < PACK_BLOCKS) {
        const int idx  = blockIdx.x * 256 + threadIdx.x;   // 0..10239
        const int kk   = idx / (NTILES * 64);
        const int rem  = idx - kk * (NTILES * 64);
        const int t    = rem >> 6;
        const int lane = rem & 63;
        const int colL = lane & 15, quad = lane >> 4;
        const int col  = t * 16 + colL;
        const int k0   = kk * 32 + quad * 8;
        float v[8];
        #pragma unroll
        for (int j = 0; j < 8; ++j) {
            const int k = k0 + j;
            v[j] = (col < IN_CH) ? W[(size_t)k * IN_CH + col]
                                 : Wres[(size_t)k * OUT_CH + (col - IN_CH)];
        }
        uint4 u;
        u.x = pack2(v[0], v[1]); u.y = pack2(v[2], v[3]);
        u.z = pack2(v[4], v[5]); u.w = pack2(v[6], v[7]);
        Bp[(kk * NTILES + t) * 64 + lane] = u;
    } else {
        const int e = (blockIdx.x - PACK_BLOCKS) * 256 + threadIdx.x;
        if (e < N_NODES) fill[e] = 0;
        if (e < N_EDGES) atomicAdd(&cnt[ei[N_EDGES + e]], 1);
    }
}

// ---------------------------------------------------------------------------
// 2-level exclusive scan: scan_local over 256-chunks + scan_bsum over the
// 196 block sums. Consumers add bsumx[i>>8].
// ---------------------------------------------------------------------------
__global__ __launch_bounds__(256) void scan_local(
    const int* __restrict__ cnt, int* __restrict__ lscan, int* __restrict__ bsum)
{
    __shared__ int ws[4];
    const int t = threadIdx.x, lane = t & 63, w = t >> 6;
    const int i = blockIdx.x * 256 + t;
    const int v = (i < N_NODES) ? cnt[i] : 0;
    int sc = v;
    #pragma unroll
    for (int off = 1; off < 64; off <<= 1) {
        const int n = __shfl_up(sc, off);
        if (lane >= off) sc += n;
    }
    if (lane == 63) ws[w] = sc;
    __syncthreads();
    int prefix = 0;
    for (int j = 0; j < w; ++j) prefix += ws[j];
    if (i < N_NODES) lscan[i] = prefix + sc - v;
    if (t == 255) bsum[blockIdx.x] = prefix + sc;
}

__global__ __launch_bounds__(256) void scan_bsum(
    const int* __restrict__ bsum, int* __restrict__ bsumx, int nblk)
{
    __shared__ int ws[4];
    const int t = threadIdx.x, lane = t & 63, w = t >> 6;
    const int v = (t < nblk) ? bsum[t] : 0;
    int sc = v;
    #pragma unroll
    for (int off = 1; off < 64; off <<= 1) {
        const int n = __shfl_up(sc, off);
        if (lane >= off) sc += n;
    }
    if (lane == 63) ws[w] = sc;
    __syncthreads();
    int prefix = 0;
    for (int j = 0; j < w; ++j) prefix += ws[j];
    if (t < nblk) bsumx[t] = prefix + sc - v;
}

// ---------------------------------------------------------------------------
// gemm_scatter: fused independent kernels via blockIdx split.
//   blocks [0, GEMM_BLOCKS)            : MFMA node transform (as R6)
//   blocks [GEMM_BLOCKS, +SCAT_BLOCKS) : CSR scatter
// Stream order would serialize them; fusion lets scatter's atomic latency
// hide under gemm's MFMA + staging work on shared CUs.
// gemm: wave wv owns col-tiles {wv,4+wv,8+wv,12+wv,16+wv} over 4 row-groups;
// C/D: col=lane&15, row=(lane>>4)*4+reg. xw stored uint2 (h0,h1|h2,h3 bf16).
// ---------------------------------------------------------------------------
__global__ __launch_bounds__(256) void gemm_scatter(
    const float* __restrict__ x, const uint4* __restrict__ Bp,
    const float* __restrict__ attS, const float* __restrict__ attD,
    uint2* __restrict__ xw2, float* __restrict__ xres,
    float* __restrict__ asrc, float* __restrict__ adst,
    const int* __restrict__ ei, const int* __restrict__ lscan,
    const int* __restrict__ bsumx, int* __restrict__ fill,
    int* __restrict__ esrc)
{
    __shared__ uint4 Alds[4 * NKK * 64];   // 32 KB
    __shared__ float partS[4][4][64];      // 4 KB
    __shared__ float partD[4][4][64];      // 4 KB

    if (blockIdx.x >= GEMM_BLOCKS) {
        const int e = (blockIdx.x - GEMM_BLOCKS) * 256 + threadIdx.x;
        if (e < N_EDGES) {
            const int d = ei[N_EDGES + e];
            const int pos = atomicAdd(&fill[d], 1);
            esrc[lscan[d] + bsumx[d >> 8] + pos] = ei[e];
        }
        return;
    }

    const int tid = threadIdx.x;
    const int n0  = blockIdx.x * 64;

    #pragma unroll
    for (int i = 0; i < 8; ++i) {
        const int e    = i * 256 + tid;
        const int g    = e >> 9;
        const int kk   = (e >> 6) & 7;
        const int lane = e & 63;
        const int cL   = lane & 15, qd = lane >> 4;
        const int row  = n0 + g * 16 + cL;
        const int k0   = kk * 32 + qd * 8;
        uint4 u = make_uint4(0u, 0u, 0u, 0u);
        if (row < N_NODES) {
            const float4 a = *reinterpret_cast<const float4*>(x + (size_t)row * IN_CH + k0);
            const float4 b = *reinterpret_cast<const float4*>(x + (size_t)row * IN_CH + k0 + 4);
            u.x = pack2(a.x, a.y); u.y = pack2(a.z, a.w);
            u.z = pack2(b.x, b.y); u.w = pack2(b.z, b.w);
        }
        Alds[(g * NKK + kk) * 64 + lane] = u;
    }
    __syncthreads();

    const int lane = tid & 63;
    const int wv   = tid >> 6;
    const int colL = lane & 15, quad = lane >> 4;

    f32x4 acc[4][5];
    #pragma unroll
    for (int rg = 0; rg < 4; ++rg)
        #pragma unroll
        for (int j = 0; j < 5; ++j) acc[rg][j] = (f32x4){0.f, 0.f, 0.f, 0.f};

    for (int kk = 0; kk < NKK; ++kk) {
        uint4 bu[5];
        #pragma unroll
        for (int j = 0; j < 5; ++j)
            bu[j] = Bp[(kk * NTILES + j * 4 + wv) * 64 + lane];
        #pragma unroll
        for (int rg = 0; rg < 4; ++rg) {
            const short8 a = as_short8(Alds[(rg * NKK + kk) * 64 + lane]);
            #pragma unroll
            for (int j = 0; j < 5; ++j)
                acc[rg][j] = __builtin_amdgcn_mfma_f32_16x16x32_bf16(
                    a, as_short8(bu[j]), acc[rg][j], 0, 0, 0);
        }
    }

    #pragma unroll
    for (int h = 0; h < HEADS; ++h) {
        const float aSv = attS[h * 64 + wv * 16 + colL];
        const float aDv = attD[h * 64 + wv * 16 + colL];
        #pragma unroll
        for (int rg = 0; rg < 4; ++rg) {
            #pragma unroll
            for (int r = 0; r < 4; ++r) {
                float vs = acc[rg][h][r] * aSv;
                float vd = acc[rg][h][r] * aDv;
                #pragma unroll
                for (int off = 8; off >= 1; off >>= 1) {
                    vs += __shfl_xor(vs, off);
                    vd += __shfl_xor(vd, off);
                }
                if (colL == 0) {
                    partS[wv][h][rg * 16 + quad * 4 + r] = vs;
                    partD[wv][h][rg * 16 + quad * 4 + r] = vd;
                }
            }
        }
    }
    __syncthreads();
    {
        const int rowIB = tid & 63, h = tid >> 6;
        const int row = n0 + rowIB;
        if (row < N_NODES) {
            const float vs = partS[0][h][rowIB] + partS[1][h][rowIB]
                           + partS[2][h][rowIB] + partS[3][h][rowIB];
            const float vd = partD[0][h][rowIB] + partD[1][h][rowIB]
                           + partD[2][h][rowIB] + partD[3][h][rowIB];
            asrc[row * HEADS + h] = vs;
            adst[row * HEADS + h] = vd;
        }
    }

    #pragma unroll
    for (int rg = 0; rg < 4; ++rg) {
        #pragma unroll
        for (int r = 0; r < 4; ++r) {
            const int row = n0 + rg * 16 + quad * 4 + r;
            if (row < N_NODES) {
                xw2[(size_t)row * 64 + wv * 16 + colL] = make_uint2(
                    pack2(acc[rg][0][r], acc[rg][1][r]),
                    pack2(acc[rg][2][r], acc[rg][3][r]));
                xres[(size_t)row * OUT_CH + wv * 16 + colL] = acc[rg][4][r];
            }
        }
    }
}

// ---------------------------------------------------------------------------
// aggregate, single-pass, unnormalized head accumulators. Per 64-edge chunk:
// lane-parallel gather asrc + exp -> LDS stash; per edge: uniform-addr LDS
// broadcast + ONE dwordx2 gather + 4 fma. 4x unroll with w consumed one edge
// at a time to keep live regs ~12 (latency-bound kernel: occupancy > ILP;
// R6's 8x unroll at 48 VGPR / 44% occ regressed vs R5's 32 VGPR / 70%).
// ---------------------------------------------------------------------------
__global__ __launch_bounds__(256) void aggregate(
    const int* __restrict__ esrc, const int* __restrict__ lscan,
    const int* __restrict__ bsumx, const int* __restrict__ cnt,
    const float* __restrict__ asrc, const float* __restrict__ adst,
    const uint2* __restrict__ xw2, const float* __restrict__ xres,
    const float* __restrict__ bias, float* __restrict__ out)
{
    __shared__ float4 wbuf[4][64];
    __shared__ int    sbuf[4][64];
    const int lane = threadIdx.x & 63;
    const int wv   = threadIdx.x >> 6;
    const int d = blockIdx.x * 4 + wv;
    if (d >= N_NODES) return;
    const int row = lscan[d] + bsumx[d >> 8];
    const int deg = cnt[d];
    const float4 ad = *reinterpret_cast<const float4*>(adst + (size_t)d * 4);
    const char* xwB = (const char*)xw2;
    const int laneB = lane << 3;

    float dn0 = 0.f, dn1 = 0.f, dn2 = 0.f, dn3 = 0.f;
    float ac0 = 0.f, ac1 = 0.f, ac2 = 0.f, ac3 = 0.f;

    for (int base = 0; base < deg; base += 64) {
        const int m = min(64, deg - base);
        if (lane < m) {
            const int s = esrc[row + base + lane];
            const float4 as = *reinterpret_cast<const float4*>(asrc + (size_t)s * 4);
            const float e0 = __expf(lrelu(as.x + ad.x));
            const float e1 = __expf(lrelu(as.y + ad.y));
            const float e2 = __expf(lrelu(as.z + ad.z));
            const float e3 = __expf(lrelu(as.w + ad.w));
            dn0 += e0; dn1 += e1; dn2 += e2; dn3 += e3;
            wbuf[wv][lane] = make_float4(e0, e1, e2, e3);
            sbuf[wv][lane] = s << 9;   // *512 B node row
        }
        int j = 0;
        for (; j + 4 <= m; j += 4) {
            uint2 v0 = *(const uint2*)(xwB + sbuf[wv][j]     + laneB);
            uint2 v1 = *(const uint2*)(xwB + sbuf[wv][j + 1] + laneB);
            uint2 v2 = *(const uint2*)(xwB + sbuf[wv][j + 2] + laneB);
            uint2 v3 = *(const uint2*)(xwB + sbuf[wv][j + 3] + laneB);
            {
                const float4 w = wbuf[wv][j];
                ac0 = fmaf(w.x, bflo(v0.x), ac0); ac1 = fmaf(w.y, bfhi(v0.x), ac1);
                ac2 = fmaf(w.z, bflo(v0.y), ac2); ac3 = fmaf(w.w, bfhi(v0.y), ac3);
            }
            {
                const float4 w = wbuf[wv][j + 1];
                ac0 = fmaf(w.x, bflo(v1.x), ac0); ac1 = fmaf(w.y, bfhi(v1.x), ac1);
                ac2 = fmaf(w.z, bflo(v1.y), ac2); ac3 = fmaf(w.w, bfhi(v1.y), ac3);
            }
            {
                const float4 w = wbuf[wv][j + 2];
                ac0 = fmaf(w.x, bflo(v2.x), ac0); ac1 = fmaf(w.y, bfhi(v2.x), ac1);
                ac2 = fmaf(w.z, bflo(v2.y), ac2); ac3 = fmaf(w.w, bfhi(v2.y), ac3);
            }
            {
                const float4 w = wbuf[wv][j + 3];
                ac0 = fmaf(w.x, bflo(v3.x), ac0); ac1 = fmaf(w.y, bfhi(v3.x), ac1);
                ac2 = fmaf(w.z, bflo(v3.y), ac2); ac3 = fmaf(w.w, bfhi(v3.y), ac3);
            }
        }
        for (; j < m; ++j) {
            const float4 w = wbuf[wv][j];
            const uint2 v = *(const uint2*)(xwB + sbuf[wv][j] + laneB);
            ac0 = fmaf(w.x, bflo(v.x), ac0);
            ac1 = fmaf(w.y, bfhi(v.x), ac1);
            ac2 = fmaf(w.z, bflo(v.y), ac2);
            ac3 = fmaf(w.w, bfhi(v.y), ac3);
        }
    }

    #pragma unroll
    for (int off = 32; off >= 1; off >>= 1) {
        dn0 += __shfl_xor(dn0, off);
        dn1 += __shfl_xor(dn1, off);
        dn2 += __shfl_xor(dn2, off);
        dn3 += __shfl_xor(dn3, off);
    }
    // self-loop
    const float4 asd = *reinterpret_cast<const float4*>(asrc + (size_t)d * 4);
    const float s0 = __expf(lrelu(asd.x + ad.x));
    const float s1 = __expf(lrelu(asd.y + ad.y));
    const float s2 = __expf(lrelu(asd.z + ad.z));
    const float s3 = __expf(lrelu(asd.w + ad.w));
    const uint2 u = xw2[(size_t)d * 64 + lane];
    ac0 = fmaf(s0, bflo(u.x), ac0); ac1 = fmaf(s1, bfhi(u.x), ac1);
    ac2 = fmaf(s2, bflo(u.y), ac2); ac3 = fmaf(s3, bfhi(u.y), ac3);
    const float i0 = 0.25f / (dn0 + s0);
    const float i1 = 0.25f / (dn1 + s1);
    const float i2 = 0.25f / (dn2 + s2);
    const float i3 = 0.25f / (dn3 + s3);
    const float v = ac0 * i0 + ac1 * i1 + ac2 * i2 + ac3 * i3
                  + bias[lane] + xres[(size_t)d * OUT_CH + lane];
    out[(size_t)d * OUT_CH + lane] = fmaxf(v, 0.f);
}

extern "C" void kernel_launch(void* const* d_in, const int* in_sizes, int n_in,
                              void* d_out, int out_size, void* d_ws, size_t ws_size,
                              hipStream_t stream) {
    const float* x    = (const float*)d_in[0];
    const int*   ei   = (const int*)d_in[1];
    const float* W    = (const float*)d_in[2];
    const float* attS = (const float*)d_in[3];
    const float* attD = (const float*)d_in[4];
    const float* bias = (const float*)d_in[5];
    const float* Wres = (const float*)d_in[6];
    float* out = (float*)d_out;

    char* p = (char*)d_ws;
    uint4*    Bp    = (uint4*)p;    p += (size_t)NKK * NTILES * 64 * 16;  // 160 KB
    uint2*    xw2   = (uint2*)p;    p += (size_t)N_NODES * 64 * 8;        // 25.6 MB
    float*    xres  = (float*)p;    p += (size_t)N_NODES * OUT_CH * 4;    // 12.8 MB
    float*    asrc  = (float*)p;    p += (size_t)N_NODES * HEADS * 4;
    float*    adst  = (float*)p;    p += (size_t)N_NODES * HEADS * 4;
    int*      cnt   = (int*)p;      p += (size_t)N_NODES * 4;
    int*      fill  = (int*)p;      p += (size_t)N_NODES * 4;
    int*      lscan = (int*)p;      p += (size_t)N_NODES * 4;
    int*      bsum  = (int*)p;      p += 256 * 4;
    int*      bsumx = (int*)p;      p += 256 * 4;
    int*      esrc  = (int*)p;      p += (size_t)N_EDGES * 4;

    const int nblk_scan = (N_NODES + 255) / 256;   // 196

    hipMemsetAsync(cnt, 0, (size_t)N_NODES * sizeof(int), stream);

    prep<<<PACK_BLOCKS + (N_EDGES + 255) / 256, 256, 0, stream>>>(
        W, Wres, Bp, ei, cnt, fill);
    scan_local<<<nblk_scan, 256, 0, stream>>>(cnt, lscan, bsum);
    scan_bsum<<<1, 256, 0, stream>>>(bsum, bsumx, nblk_scan);
    gemm_scatter<<<GEMM_BLOCKS + SCAT_BLOCKS, 256, 0, stream>>>(
        x, Bp, attS, attD, xw2, xres, asrc, adst,
        ei, lscan, bsumx, fill, esrc);
    aggregate<<<(N_NODES + 3) / 4, 256, 0, stream>>>(
        esrc, lscan, bsumx, cnt, asrc, adst, xw2, xres, bias, out);
}